// Round 3
// baseline (231.192 us; speedup 1.0000x reference)
//
#include <hip/hip_runtime.h>

// W4A16 GEMM, M=N=K=4096, GROUP=128, zp=8.
// Harness presents fp16 reference tensors as FLOAT32 (only bf16/f32/int are
// native); output is float32. So: x = f32 [M,K], scale = f32 [32,N],
// q_weight = int32 [K,N], out = f32 [M,N].
// Pass 1: dequant+transpose q -> Wt fp16 [N][K] in d_ws (32 MB). fp16 RNE of
//         (q-8)*scale_f32 is bit-identical to the reference's fp16 w.
// Pass 2: C = A * Wt^T, 128x128 tile, reg-staged LDS double buffer,
//         mfma_f32_16x16x32_f16, f32 accum, f32 out.

#define MDIM 4096
#define NDIM 4096
#define KDIM 4096

typedef __attribute__((ext_vector_type(8))) _Float16 f16x8;
typedef __attribute__((ext_vector_type(4))) float    f32x4;
typedef __attribute__((ext_vector_type(4))) int      i32x4;

__device__ __forceinline__ unsigned short f2h(float f) {
    union { _Float16 h; unsigned short u; } v;
    v.h = (_Float16)f;  // RNE
    return v.u;
}

// ---------------- diagnostic fallback ----------------
__global__ void zero_fill(float* __restrict__ out, int n) {
    int i = blockIdx.x * blockDim.x + threadIdx.x;
    if (i < n) out[i] = 0.f;
}

// ---------------- Pass 1: dequant + transpose ----------------
// grid (K/64, N/64), 256 threads. q[k0+64)[n0+64) -> Wt[n0+64)[k0+64) fp16.
__global__ void dequant_transpose(const int* __restrict__ q,
                                  const float* __restrict__ scale,
                                  unsigned short* __restrict__ wt) {
    __shared__ unsigned short lds[64][65];
    const int t  = threadIdx.x;
    const int k0 = blockIdx.x * 64;
    const int n0 = blockIdx.y * 64;
    const int g  = k0 >> 7;  // group index, constant across the 64-row tile

    const int r  = t >> 4;          // 0..15
    const int c4 = (t & 15) * 4;    // 0,4,...,60

    float4 s = *(const float4*)&scale[(size_t)g * NDIM + n0 + c4];

#pragma unroll
    for (int p = 0; p < 4; ++p) {
        const int kl = r + p * 16;
        int4 qv = *(const int4*)&q[(size_t)(k0 + kl) * NDIM + n0 + c4];
        lds[kl][c4 + 0] = f2h((float)(qv.x - 8) * s.x);
        lds[kl][c4 + 1] = f2h((float)(qv.y - 8) * s.y);
        lds[kl][c4 + 2] = f2h((float)(qv.z - 8) * s.z);
        lds[kl][c4 + 3] = f2h((float)(qv.w - 8) * s.w);
    }
    __syncthreads();

    const int kc = (t & 15) * 4;
#pragma unroll
    for (int p = 0; p < 4; ++p) {
        const int nl = (t >> 4) + p * 16;
        ushort4 o;
        o.x = lds[kc + 0][nl];
        o.y = lds[kc + 1][nl];
        o.z = lds[kc + 2][nl];
        o.w = lds[kc + 3][nl];
        *(ushort4*)&wt[(size_t)(n0 + nl) * KDIM + k0 + kc] = o;
    }
}

// ---------------- Pass 2: fp16 GEMM, reg-staged double buffer ----------------
// C[M][N] = A[M][K](f32, cvt->fp16) * Wt[N][K]^T(fp16). 128x128 tile, BK=32,
// 4 waves (2x2), each wave 64x64 via 4x4 fragments of mfma_f32_16x16x32_f16.
__global__ __launch_bounds__(256) void gemm_bt(const float* __restrict__ A,
                                               const unsigned short* __restrict__ Bt,
                                               float* __restrict__ C) {
    __shared__ unsigned short sA[2][128 * 32];
    __shared__ unsigned short sB[2][128 * 32];

    const int t = threadIdx.x;
    const int l = t & 63;
    const int w = t >> 6;

    const int m0 = blockIdx.y * 128;
    const int n0 = blockIdx.x * 128;

    const float*          Arow = A  + (size_t)m0 * KDIM;
    const unsigned short* Brow = Bt + (size_t)n0 * KDIM;

    // staging geometry: thread t covers 8-elem chunks t and t+256 of the
    // 128x32 tile: rows r0 and r0+64, cols c0..c0+7.
    const int r0 = t >> 2;        // 0..63
    const int c0 = (t & 3) * 8;   // 0,8,16,24

    float4 fa[4];   // A rows r0, r0+64 (8 f32 each)
    i32x4  pb0, pb1;
    auto gload = [&](int kt) {
        const size_t oa0 = (size_t)r0 * KDIM + (size_t)kt * 32 + c0;
        const size_t oa1 = (size_t)(r0 + 64) * KDIM + (size_t)kt * 32 + c0;
        fa[0] = *(const float4*)(Arow + oa0);
        fa[1] = *(const float4*)(Arow + oa0 + 4);
        fa[2] = *(const float4*)(Arow + oa1);
        fa[3] = *(const float4*)(Arow + oa1 + 4);
        pb0 = *(const i32x4*)(Brow + oa0);
        pb1 = *(const i32x4*)(Brow + oa1);
    };
    auto pack8 = [&](float4 a, float4 b) {
        f16x8 r;
        r[0] = (_Float16)a.x; r[1] = (_Float16)a.y;
        r[2] = (_Float16)a.z; r[3] = (_Float16)a.w;
        r[4] = (_Float16)b.x; r[5] = (_Float16)b.y;
        r[6] = (_Float16)b.z; r[7] = (_Float16)b.w;
        return r;
    };
    auto swrite = [&](int buf) {
        *(f16x8*)&sA[buf][r0 * 32 + c0]        = pack8(fa[0], fa[1]);
        *(f16x8*)&sA[buf][(r0 + 64) * 32 + c0] = pack8(fa[2], fa[3]);
        *(i32x4*)&sB[buf][r0 * 32 + c0]        = pb0;
        *(i32x4*)&sB[buf][(r0 + 64) * 32 + c0] = pb1;
    };

    f32x4 acc[4][4];
#pragma unroll
    for (int mi = 0; mi < 4; ++mi)
#pragma unroll
        for (int ni = 0; ni < 4; ++ni)
            acc[mi][ni] = (f32x4){0.f, 0.f, 0.f, 0.f};

    const int wm = (w >> 1) * 64;  // wave row offset in tile
    const int wn = (w & 1) * 64;   // wave col offset in tile
    const int lr = l & 15;
    const int lk = (l >> 4) * 8;

    gload(0);
    swrite(0);

    const int NT = KDIM / 32;  // 128
    for (int kt = 0; kt < NT; ++kt) {
        const int cur = kt & 1;
        __syncthreads();  // buf[cur] visible; prior readers of buf[cur^1] done
        if (kt + 1 < NT) gload(kt + 1);  // issue early, consume after MFMA

        f16x8 a[4], b[4];
#pragma unroll
        for (int mi = 0; mi < 4; ++mi)
            a[mi] = *(const f16x8*)&sA[cur][(wm + mi * 16 + lr) * 32 + lk];
#pragma unroll
        for (int ni = 0; ni < 4; ++ni)
            b[ni] = *(const f16x8*)&sB[cur][(wn + ni * 16 + lr) * 32 + lk];

#pragma unroll
        for (int mi = 0; mi < 4; ++mi)
#pragma unroll
            for (int ni = 0; ni < 4; ++ni)
                acc[mi][ni] = __builtin_amdgcn_mfma_f32_16x16x32_f16(
                    a[mi], b[ni], acc[mi][ni], 0, 0, 0);

        if (kt + 1 < NT) swrite(cur ^ 1);  // write-late; next barrier drains lgkm
    }

    // epilogue: D layout col = lane&15, row = (lane>>4)*4 + reg (m89-verified)
#pragma unroll
    for (int mi = 0; mi < 4; ++mi) {
#pragma unroll
        for (int ni = 0; ni < 4; ++ni) {
            const int row = m0 + wm + mi * 16 + (l >> 4) * 4;
            const int col = n0 + wn + ni * 16 + lr;
#pragma unroll
            for (int r2 = 0; r2 < 4; ++r2)
                C[(size_t)(row + r2) * NDIM + col] = acc[mi][ni][r2];
        }
    }
}

extern "C" void kernel_launch(void* const* d_in, const int* in_sizes, int n_in,
                              void* d_out, int out_size, void* d_ws, size_t ws_size,
                              hipStream_t stream) {
    const float* x     = (const float*)d_in[0];  // f32 (fp16-valued) [M,K]
    const float* scale = (const float*)d_in[1];  // f32 (fp16-valued) [K/128,N]
    const int*   qw    = (const int*)d_in[2];    // int32 [K,N], values 0..15
    float*       out   = (float*)d_out;          // f32 [M,N]
    unsigned short* wt = (unsigned short*)d_ws;  // fp16 [N,K] scratch (32 MB)

    const size_t need = (size_t)NDIM * KDIM * 2;  // 32 MB
    if (ws_size < need) {
        // diagnostic: if this runs, absmax reads ~= max|ref| (~11.75)
        zero_fill<<<(out_size + 255) / 256, 256, 0, stream>>>(out, out_size);
        return;
    }

    dequant_transpose<<<dim3(KDIM / 64, NDIM / 64), 256, 0, stream>>>(qw, scale, wt);
    gemm_bt<<<dim3(NDIM / 128, MDIM / 128), 256, 0, stream>>>(x, wt, out);
}

// Round 4
// 228.188 us; speedup vs baseline: 1.0132x; 1.0132x over previous
//
#include <hip/hip_runtime.h>

// W4A16 GEMM, M=N=K=4096, GROUP=128, zp=8.
// Inputs (harness presents fp16 as f32): x f32[M,K], scale f32[32,N],
// q_weight int32[K,N] (0..15). Output f32[M,N].
//
// Fast path (ws >= 64MB):
//   P0 convert_x: x f32 -> Xh fp16 [M,K]           (ws + 32MB)
//   P1 dequant_transpose: q -> Wt fp16 [N,K]       (ws)
//   P2 gemm_glds: C = Xh * Wt^T, m97 structure (128x128 tile, BK=32,
//      global_load_lds width-16 staging, double-buffered LDS, 16x16x32 f16 MFMA)
// Fallback (ws >= 32MB): proven round-3 reg-staged GEMM reading x as f32.

#define MDIM 4096
#define NDIM 4096
#define KDIM 4096

typedef __attribute__((ext_vector_type(8))) _Float16 f16x8;
typedef __attribute__((ext_vector_type(4))) float    f32x4;
typedef __attribute__((ext_vector_type(4))) int      i32x4;

__device__ __forceinline__ unsigned short f2h(float f) {
    union { _Float16 h; unsigned short u; } v;
    v.h = (_Float16)f;  // RNE
    return v.u;
}

// ---------------- diagnostic fallback ----------------
__global__ void zero_fill(float* __restrict__ out, int n) {
    int i = blockIdx.x * blockDim.x + threadIdx.x;
    if (i < n) out[i] = 0.f;
}

// ---------------- P0: x f32 -> fp16 ----------------
__global__ void convert_x(const float* __restrict__ x,
                          unsigned short* __restrict__ xh, int n8) {
    int i = blockIdx.x * blockDim.x + threadIdx.x;
    const int stride = gridDim.x * blockDim.x;
    for (; i < n8; i += stride) {
        const float4 a = ((const float4*)x)[(size_t)i * 2];
        const float4 b = ((const float4*)x)[(size_t)i * 2 + 1];
        f16x8 r;
        r[0] = (_Float16)a.x; r[1] = (_Float16)a.y;
        r[2] = (_Float16)a.z; r[3] = (_Float16)a.w;
        r[4] = (_Float16)b.x; r[5] = (_Float16)b.y;
        r[6] = (_Float16)b.z; r[7] = (_Float16)b.w;
        *(f16x8*)&xh[(size_t)i * 8] = r;
    }
}

// ---------------- P1: dequant + transpose ----------------
// grid (K/64, N/64), 256 threads. q[k0+64)[n0+64) -> Wt[n0+64)[k0+64) fp16.
__global__ void dequant_transpose(const int* __restrict__ q,
                                  const float* __restrict__ scale,
                                  unsigned short* __restrict__ wt) {
    __shared__ unsigned short lds[64][65];
    const int t  = threadIdx.x;
    const int k0 = blockIdx.x * 64;
    const int n0 = blockIdx.y * 64;
    const int g  = k0 >> 7;  // group index, constant across the 64-row tile

    const int r  = t >> 4;          // 0..15
    const int c4 = (t & 15) * 4;    // 0,4,...,60

    float4 s = *(const float4*)&scale[(size_t)g * NDIM + n0 + c4];

#pragma unroll
    for (int p = 0; p < 4; ++p) {
        const int kl = r + p * 16;
        int4 qv = *(const int4*)&q[(size_t)(k0 + kl) * NDIM + n0 + c4];
        lds[kl][c4 + 0] = f2h((float)(qv.x - 8) * s.x);
        lds[kl][c4 + 1] = f2h((float)(qv.y - 8) * s.y);
        lds[kl][c4 + 2] = f2h((float)(qv.z - 8) * s.z);
        lds[kl][c4 + 3] = f2h((float)(qv.w - 8) * s.w);
    }
    __syncthreads();

    const int kc = (t & 15) * 4;
#pragma unroll
    for (int p = 0; p < 4; ++p) {
        const int nl = (t >> 4) + p * 16;
        ushort4 o;
        o.x = lds[kc + 0][nl];
        o.y = lds[kc + 1][nl];
        o.z = lds[kc + 2][nl];
        o.w = lds[kc + 3][nl];
        *(ushort4*)&wt[(size_t)(n0 + nl) * KDIM + k0 + kc] = o;
    }
}

// ---------------- P2 fast: m97-structure GEMM, global_load_lds ----------------
// C[M][N] = Xh[M][K] * Wt[N][K]^T. 128x128 tile, BK=32, 4 waves (2x2),
// each wave 64x64 via 4x4 fragments of mfma_f32_16x16x32_f16.
// Staging: 2x global_load_lds_dwordx4 per operand per wave (linear LDS dest =
// wave-uniform base + lane*16; per-lane global src).
__global__ __launch_bounds__(256) void gemm_glds(const unsigned short* __restrict__ A,
                                                 const unsigned short* __restrict__ Bt,
                                                 float* __restrict__ C) {
    __shared__ unsigned short sA[2][128 * 32];
    __shared__ unsigned short sB[2][128 * 32];

    const int t = threadIdx.x;
    const int w = t >> 6;
    const int l = t & 63;

    const int m0 = blockIdx.y * 128;
    const int n0 = blockIdx.x * 128;

    // lane l of wave w, issue i covers tile row i*64 + w*16 + (l>>2),
    // elem cols (l&3)*8 .. +8; LDS dest elems base = i*2048 + w*512 (+ l*8).
    const int srow = w * 16 + (l >> 2);
    const int scol = (l & 3) * 8;

    auto stage = [&](int buf, int kt) {
#pragma unroll
        for (int i = 0; i < 2; ++i) {
            const int row = i * 64 + srow;
            const unsigned short* ga = A  + (size_t)(m0 + row) * KDIM + (size_t)kt * 32 + scol;
            const unsigned short* gb = Bt + (size_t)(n0 + row) * KDIM + (size_t)kt * 32 + scol;
            unsigned short* la = &sA[buf][i * 2048 + w * 512];
            unsigned short* lb = &sB[buf][i * 2048 + w * 512];
            __builtin_amdgcn_global_load_lds(
                (const __attribute__((address_space(1))) unsigned int*)ga,
                (__attribute__((address_space(3))) unsigned int*)la, 16, 0, 0);
            __builtin_amdgcn_global_load_lds(
                (const __attribute__((address_space(1))) unsigned int*)gb,
                (__attribute__((address_space(3))) unsigned int*)lb, 16, 0, 0);
        }
    };

    f32x4 acc[4][4];
#pragma unroll
    for (int mi = 0; mi < 4; ++mi)
#pragma unroll
        for (int ni = 0; ni < 4; ++ni)
            acc[mi][ni] = (f32x4){0.f, 0.f, 0.f, 0.f};

    const int wm = (w >> 1) * 64;
    const int wn = (w & 1) * 64;
    const int lr = l & 15;
    const int lk = (l >> 4) * 8;

    stage(0, 0);

    const int NT = KDIM / 32;  // 128
    for (int kt = 0; kt < NT; ++kt) {
        const int cur = kt & 1;
        __syncthreads();  // drains vmcnt(0): buf[cur] staged; buf[cur^1] readers done
        if (kt + 1 < NT) stage(cur ^ 1, kt + 1);

        f16x8 a[4], b[4];
#pragma unroll
        for (int mi = 0; mi < 4; ++mi)
            a[mi] = *(const f16x8*)&sA[cur][(wm + mi * 16 + lr) * 32 + lk];
#pragma unroll
        for (int ni = 0; ni < 4; ++ni)
            b[ni] = *(const f16x8*)&sB[cur][(wn + ni * 16 + lr) * 32 + lk];

#pragma unroll
        for (int mi = 0; mi < 4; ++mi)
#pragma unroll
            for (int ni = 0; ni < 4; ++ni)
                acc[mi][ni] = __builtin_amdgcn_mfma_f32_16x16x32_f16(
                    a[mi], b[ni], acc[mi][ni], 0, 0, 0);
    }

    // epilogue: D layout col = lane&15, row = (lane>>4)*4 + reg (m89-verified)
#pragma unroll
    for (int mi = 0; mi < 4; ++mi) {
#pragma unroll
        for (int ni = 0; ni < 4; ++ni) {
            const int row = m0 + wm + mi * 16 + (l >> 4) * 4;
            const int col = n0 + wn + ni * 16 + lr;
#pragma unroll
            for (int r2 = 0; r2 < 4; ++r2)
                C[(size_t)(row + r2) * NDIM + col] = acc[mi][ni][r2];
        }
    }
}

// ---------------- P2 fallback: round-3 reg-staged GEMM (proven) ----------------
__global__ __launch_bounds__(256) void gemm_bt(const float* __restrict__ A,
                                               const unsigned short* __restrict__ Bt,
                                               float* __restrict__ C) {
    __shared__ unsigned short sA[2][128 * 32];
    __shared__ unsigned short sB[2][128 * 32];

    const int t = threadIdx.x;
    const int l = t & 63;
    const int w = t >> 6;

    const int m0 = blockIdx.y * 128;
    const int n0 = blockIdx.x * 128;

    const float*          Arow = A  + (size_t)m0 * KDIM;
    const unsigned short* Brow = Bt + (size_t)n0 * KDIM;

    const int r0 = t >> 2;
    const int c0 = (t & 3) * 8;

    float4 fa[4];
    i32x4  pb0, pb1;
    auto gload = [&](int kt) {
        const size_t oa0 = (size_t)r0 * KDIM + (size_t)kt * 32 + c0;
        const size_t oa1 = (size_t)(r0 + 64) * KDIM + (size_t)kt * 32 + c0;
        fa[0] = *(const float4*)(Arow + oa0);
        fa[1] = *(const float4*)(Arow + oa0 + 4);
        fa[2] = *(const float4*)(Arow + oa1);
        fa[3] = *(const float4*)(Arow + oa1 + 4);
        pb0 = *(const i32x4*)(Brow + oa0);
        pb1 = *(const i32x4*)(Brow + oa1);
    };
    auto pack8 = [&](float4 a, float4 b) {
        f16x8 r;
        r[0] = (_Float16)a.x; r[1] = (_Float16)a.y;
        r[2] = (_Float16)a.z; r[3] = (_Float16)a.w;
        r[4] = (_Float16)b.x; r[5] = (_Float16)b.y;
        r[6] = (_Float16)b.z; r[7] = (_Float16)b.w;
        return r;
    };
    auto swrite = [&](int buf) {
        *(f16x8*)&sA[buf][r0 * 32 + c0]        = pack8(fa[0], fa[1]);
        *(f16x8*)&sA[buf][(r0 + 64) * 32 + c0] = pack8(fa[2], fa[3]);
        *(i32x4*)&sB[buf][r0 * 32 + c0]        = pb0;
        *(i32x4*)&sB[buf][(r0 + 64) * 32 + c0] = pb1;
    };

    f32x4 acc[4][4];
#pragma unroll
    for (int mi = 0; mi < 4; ++mi)
#pragma unroll
        for (int ni = 0; ni < 4; ++ni)
            acc[mi][ni] = (f32x4){0.f, 0.f, 0.f, 0.f};

    const int wm = (w >> 1) * 64;
    const int wn = (w & 1) * 64;
    const int lr = l & 15;
    const int lk = (l >> 4) * 8;

    gload(0);
    swrite(0);

    const int NT = KDIM / 32;
    for (int kt = 0; kt < NT; ++kt) {
        const int cur = kt & 1;
        __syncthreads();
        if (kt + 1 < NT) gload(kt + 1);

        f16x8 a[4], b[4];
#pragma unroll
        for (int mi = 0; mi < 4; ++mi)
            a[mi] = *(const f16x8*)&sA[cur][(wm + mi * 16 + lr) * 32 + lk];
#pragma unroll
        for (int ni = 0; ni < 4; ++ni)
            b[ni] = *(const f16x8*)&sB[cur][(wn + ni * 16 + lr) * 32 + lk];

#pragma unroll
        for (int mi = 0; mi < 4; ++mi)
#pragma unroll
            for (int ni = 0; ni < 4; ++ni)
                acc[mi][ni] = __builtin_amdgcn_mfma_f32_16x16x32_f16(
                    a[mi], b[ni], acc[mi][ni], 0, 0, 0);

        if (kt + 1 < NT) swrite(cur ^ 1);
    }

#pragma unroll
    for (int mi = 0; mi < 4; ++mi) {
#pragma unroll
        for (int ni = 0; ni < 4; ++ni) {
            const int row = m0 + wm + mi * 16 + (l >> 4) * 4;
            const int col = n0 + wn + ni * 16 + lr;
#pragma unroll
            for (int r2 = 0; r2 < 4; ++r2)
                C[(size_t)(row + r2) * NDIM + col] = acc[mi][ni][r2];
        }
    }
}

extern "C" void kernel_launch(void* const* d_in, const int* in_sizes, int n_in,
                              void* d_out, int out_size, void* d_ws, size_t ws_size,
                              hipStream_t stream) {
    const float* x     = (const float*)d_in[0];
    const float* scale = (const float*)d_in[1];
    const int*   qw    = (const int*)d_in[2];
    float*       out   = (float*)d_out;

    const size_t wtBytes = (size_t)NDIM * KDIM * 2;  // 32 MB
    const size_t xhBytes = (size_t)MDIM * KDIM * 2;  // 32 MB

    if (ws_size >= wtBytes + xhBytes) {
        unsigned short* wt = (unsigned short*)d_ws;
        unsigned short* xh = (unsigned short*)((char*)d_ws + wtBytes);
        convert_x<<<2048, 256, 0, stream>>>(x, xh, MDIM * KDIM / 8);
        dequant_transpose<<<dim3(KDIM / 64, NDIM / 64), 256, 0, stream>>>(qw, scale, wt);
        gemm_glds<<<dim3(NDIM / 128, MDIM / 128), 256, 0, stream>>>(xh, wt, out);
    } else if (ws_size >= wtBytes) {
        unsigned short* wt = (unsigned short*)d_ws;
        dequant_transpose<<<dim3(KDIM / 64, NDIM / 64), 256, 0, stream>>>(qw, scale, wt);
        gemm_bt<<<dim3(NDIM / 128, MDIM / 128), 256, 0, stream>>>(x, wt, out);
    } else {
        zero_fill<<<(out_size + 255) / 256, 256, 0, stream>>>(out, out_size);
    }
}

// Round 5
// 157.878 us; speedup vs baseline: 1.4644x; 1.4453x over previous
//
#include <hip/hip_runtime.h>

// W4A16 GEMM, M=N=K=4096, GROUP=128, zp=8.
// Inputs (harness presents fp16 as f32): x f32[M,K], scale f32[32,N],
// q_weight int32[K,N] (0..15). Output f32[M,N].
//
// Fast path (ws >= 64MB):
//   P0 convert_x: x f32 -> Xh fp16 [M,K]
//   P1 dequant_transpose: q -> Wt fp16 [N,K]
//   P2 gemm_8w: 256x256 tile, BK=64, 8 waves, double-buffered LDS with
//      counted vmcnt(8) (never drain to 0 in loop), global_load_lds width-16,
//      read-side XOR swizzle chunk^(row&7) (source pre-swizzled), 16x16x32 f16
//      MFMA, XCD-aware block swizzle.
// Fallback (ws >= 32MB): proven round-3 reg-staged 128x128 GEMM.

#define MDIM 4096
#define NDIM 4096
#define KDIM 4096

typedef __attribute__((ext_vector_type(8))) _Float16 f16x8;
typedef __attribute__((ext_vector_type(4))) float    f32x4;
typedef __attribute__((ext_vector_type(4))) int      i32x4;

__device__ __forceinline__ unsigned short f2h(float f) {
    union { _Float16 h; unsigned short u; } v;
    v.h = (_Float16)f;  // RNE
    return v.u;
}

// ---------------- diagnostic fallback ----------------
__global__ void zero_fill(float* __restrict__ out, int n) {
    int i = blockIdx.x * blockDim.x + threadIdx.x;
    if (i < n) out[i] = 0.f;
}

// ---------------- P0: x f32 -> fp16 ----------------
__global__ void convert_x(const float* __restrict__ x,
                          unsigned short* __restrict__ xh, int n8) {
    int i = blockIdx.x * blockDim.x + threadIdx.x;
    const int stride = gridDim.x * blockDim.x;
    for (; i < n8; i += stride) {
        const float4 a = ((const float4*)x)[(size_t)i * 2];
        const float4 b = ((const float4*)x)[(size_t)i * 2 + 1];
        f16x8 r;
        r[0] = (_Float16)a.x; r[1] = (_Float16)a.y;
        r[2] = (_Float16)a.z; r[3] = (_Float16)a.w;
        r[4] = (_Float16)b.x; r[5] = (_Float16)b.y;
        r[6] = (_Float16)b.z; r[7] = (_Float16)b.w;
        *(f16x8*)&xh[(size_t)i * 8] = r;
    }
}

// ---------------- P1: dequant + transpose ----------------
__global__ void dequant_transpose(const int* __restrict__ q,
                                  const float* __restrict__ scale,
                                  unsigned short* __restrict__ wt) {
    __shared__ unsigned short lds[64][65];
    const int t  = threadIdx.x;
    const int k0 = blockIdx.x * 64;
    const int n0 = blockIdx.y * 64;
    const int g  = k0 >> 7;

    const int r  = t >> 4;
    const int c4 = (t & 15) * 4;

    float4 s = *(const float4*)&scale[(size_t)g * NDIM + n0 + c4];

#pragma unroll
    for (int p = 0; p < 4; ++p) {
        const int kl = r + p * 16;
        int4 qv = *(const int4*)&q[(size_t)(k0 + kl) * NDIM + n0 + c4];
        lds[kl][c4 + 0] = f2h((float)(qv.x - 8) * s.x);
        lds[kl][c4 + 1] = f2h((float)(qv.y - 8) * s.y);
        lds[kl][c4 + 2] = f2h((float)(qv.z - 8) * s.z);
        lds[kl][c4 + 3] = f2h((float)(qv.w - 8) * s.w);
    }
    __syncthreads();

    const int kc = (t & 15) * 4;
#pragma unroll
    for (int p = 0; p < 4; ++p) {
        const int nl = (t >> 4) + p * 16;
        ushort4 o;
        o.x = lds[kc + 0][nl];
        o.y = lds[kc + 1][nl];
        o.z = lds[kc + 2][nl];
        o.w = lds[kc + 3][nl];
        *(ushort4*)&wt[(size_t)(n0 + nl) * KDIM + k0 + kc] = o;
    }
}

// ---------------- P2 fast: 256x256 8-wave counted-vmcnt GEMM ----------------
// LDS layout per buffer: A [256 rows][8 chunks of 8 halfs], B same, +16384.
// Physical chunk holds logical chunk^(row&7) (involution). Stage writes
// linearly (global_load_lds), with the SOURCE column pre-XORed; ds_read
// applies the same XOR.
__global__ __launch_bounds__(512, 2) void gemm_8w(const unsigned short* __restrict__ A,
                                                  const unsigned short* __restrict__ Bt,
                                                  float* __restrict__ C) {
    __shared__ unsigned short lds[65536];  // 128 KiB: 2 x (A 16384 + B 16384)

    const int t = threadIdx.x;
    const int w = t >> 6;   // wave 0..7
    const int l = t & 63;

    // XCD-aware bijective swizzle: 256 wgs, 8 XCDs -> 32 contiguous tiles/XCD
    const int orig = blockIdx.x;
    const int wg = (orig & 7) * 32 + (orig >> 3);
    const int bx = wg & 15;   // N tile
    const int by = wg >> 4;   // M tile
    const int m0 = by * 256;
    const int n0 = bx * 256;

    const int wr = w >> 2;    // 0..1 : wave row (128 rows)
    const int wc = w & 3;     // 0..3 : wave col (64 cols)

    // ---- staging geometry (per-lane, swizzled source) ----
    const int lr8 = l >> 3;                  // row within 8-row group
    const int sc  = ((l & 7) ^ lr8) * 8;     // swizzled source col (halfs)
    const unsigned short* pa = A  + (size_t)(m0 + w * 8 + lr8) * KDIM + sc;
    const unsigned short* pb = Bt + (size_t)(n0 + w * 8 + lr8) * KDIM + sc;

    auto stage = [&](int buf, int kt) {
        const int kof = kt * 64;
        unsigned short* base = &lds[buf * 32768];
#pragma unroll
        for (int i = 0; i < 4; ++i)
            __builtin_amdgcn_global_load_lds(
                (const __attribute__((address_space(1))) unsigned int*)(pa + (size_t)i * 64 * KDIM + kof),
                (__attribute__((address_space(3))) unsigned int*)(base + i * 4096 + w * 512), 16, 0, 0);
#pragma unroll
        for (int i = 0; i < 4; ++i)
            __builtin_amdgcn_global_load_lds(
                (const __attribute__((address_space(1))) unsigned int*)(pb + (size_t)i * 64 * KDIM + kof),
                (__attribute__((address_space(3))) unsigned int*)(base + 16384 + i * 4096 + w * 512), 16, 0, 0);
    };

    // ---- fragment-read geometry ----
    const int lr = l & 15;    // frag row
    const int hi = l >> 4;    // 0..3 : k sub-chunk
    const int ca0 = ((hi + 0) ^ (l & 7)) * 8;  // phys chunk offset, k-step 0
    const int ca1 = ((hi + 4) ^ (l & 7)) * 8;  // phys chunk offset, k-step 1
    const int arow = wr * 128 + lr;
    const int brow = wc * 64 + lr;

    f32x4 acc[8][4];
#pragma unroll
    for (int mi = 0; mi < 8; ++mi)
#pragma unroll
        for (int ni = 0; ni < 4; ++ni)
            acc[mi][ni] = (f32x4){0.f, 0.f, 0.f, 0.f};

    stage(0, 0);
    stage(1, 1);

    const int NT = KDIM / 64;  // 64
    for (int kt = 0; kt < NT; ++kt) {
        if (kt == NT - 1)
            asm volatile("s_waitcnt vmcnt(0)" ::: "memory");
        else
            asm volatile("s_waitcnt vmcnt(8)" ::: "memory");  // tile kt landed; next stays in flight
        __builtin_amdgcn_s_barrier();

        const int b = kt & 1;
        const unsigned short* sA = &lds[b * 32768];
        const unsigned short* sB = &lds[b * 32768 + 16384];

        f16x8 a0[8], a1[8], b0[4], b1[4];
#pragma unroll
        for (int mi = 0; mi < 8; ++mi) {
            a0[mi] = *(const f16x8*)&sA[(arow + mi * 16) * 64 + ca0];
            a1[mi] = *(const f16x8*)&sA[(arow + mi * 16) * 64 + ca1];
        }
#pragma unroll
        for (int ni = 0; ni < 4; ++ni) {
            b0[ni] = *(const f16x8*)&sB[(brow + ni * 16) * 64 + ca0];
            b1[ni] = *(const f16x8*)&sB[(brow + ni * 16) * 64 + ca1];
        }
        asm volatile("s_waitcnt lgkmcnt(0)" ::: "memory");  // frags in regs
        __builtin_amdgcn_s_barrier();                        // all waves done reading buf b
        if (kt + 2 < NT) stage(b, kt + 2);                   // overwrite buf b; awaited at kt+2
        __builtin_amdgcn_sched_barrier(0);                   // keep stage issues before MFMA wall

        __builtin_amdgcn_s_setprio(1);
#pragma unroll
        for (int mi = 0; mi < 8; ++mi)
#pragma unroll
            for (int ni = 0; ni < 4; ++ni)
                acc[mi][ni] = __builtin_amdgcn_mfma_f32_16x16x32_f16(
                    a0[mi], b0[ni], acc[mi][ni], 0, 0, 0);
#pragma unroll
        for (int mi = 0; mi < 8; ++mi)
#pragma unroll
            for (int ni = 0; ni < 4; ++ni)
                acc[mi][ni] = __builtin_amdgcn_mfma_f32_16x16x32_f16(
                    a1[mi], b1[ni], acc[mi][ni], 0, 0, 0);
        __builtin_amdgcn_s_setprio(0);
    }

    // epilogue: D layout col = lane&15, row = (lane>>4)*4 + reg
#pragma unroll
    for (int mi = 0; mi < 8; ++mi) {
#pragma unroll
        for (int ni = 0; ni < 4; ++ni) {
            const int row = m0 + wr * 128 + mi * 16 + hi * 4;
            const int col = n0 + wc * 64 + ni * 16 + lr;
#pragma unroll
            for (int r2 = 0; r2 < 4; ++r2)
                C[(size_t)(row + r2) * NDIM + col] = acc[mi][ni][r2];
        }
    }
}

// ---------------- P2 fallback: round-3 reg-staged GEMM (proven) ----------------
__global__ __launch_bounds__(256) void gemm_bt(const float* __restrict__ A,
                                               const unsigned short* __restrict__ Bt,
                                               float* __restrict__ C) {
    __shared__ unsigned short sA[2][128 * 32];
    __shared__ unsigned short sB[2][128 * 32];

    const int t = threadIdx.x;
    const int l = t & 63;
    const int w = t >> 6;

    const int m0 = blockIdx.y * 128;
    const int n0 = blockIdx.x * 128;

    const float*          Arow = A  + (size_t)m0 * KDIM;
    const unsigned short* Brow = Bt + (size_t)n0 * KDIM;

    const int r0 = t >> 2;
    const int c0 = (t & 3) * 8;

    float4 fa[4];
    i32x4  pb0, pb1;
    auto gload = [&](int kt) {
        const size_t oa0 = (size_t)r0 * KDIM + (size_t)kt * 32 + c0;
        const size_t oa1 = (size_t)(r0 + 64) * KDIM + (size_t)kt * 32 + c0;
        fa[0] = *(const float4*)(Arow + oa0);
        fa[1] = *(const float4*)(Arow + oa0 + 4);
        fa[2] = *(const float4*)(Arow + oa1);
        fa[3] = *(const float4*)(Arow + oa1 + 4);
        pb0 = *(const i32x4*)(Brow + oa0);
        pb1 = *(const i32x4*)(Brow + oa1);
    };
    auto pack8 = [&](float4 a, float4 b) {
        f16x8 r;
        r[0] = (_Float16)a.x; r[1] = (_Float16)a.y;
        r[2] = (_Float16)a.z; r[3] = (_Float16)a.w;
        r[4] = (_Float16)b.x; r[5] = (_Float16)b.y;
        r[6] = (_Float16)b.z; r[7] = (_Float16)b.w;
        return r;
    };
    auto swrite = [&](int buf) {
        *(f16x8*)&sA[buf][r0 * 32 + c0]        = pack8(fa[0], fa[1]);
        *(f16x8*)&sA[buf][(r0 + 64) * 32 + c0] = pack8(fa[2], fa[3]);
        *(i32x4*)&sB[buf][r0 * 32 + c0]        = pb0;
        *(i32x4*)&sB[buf][(r0 + 64) * 32 + c0] = pb1;
    };

    f32x4 acc[4][4];
#pragma unroll
    for (int mi = 0; mi < 4; ++mi)
#pragma unroll
        for (int ni = 0; ni < 4; ++ni)
            acc[mi][ni] = (f32x4){0.f, 0.f, 0.f, 0.f};

    const int wm = (w >> 1) * 64;
    const int wn = (w & 1) * 64;
    const int lr = l & 15;
    const int lk = (l >> 4) * 8;

    gload(0);
    swrite(0);

    const int NT = KDIM / 32;
    for (int kt = 0; kt < NT; ++kt) {
        const int cur = kt & 1;
        __syncthreads();
        if (kt + 1 < NT) gload(kt + 1);

        f16x8 a[4], b[4];
#pragma unroll
        for (int mi = 0; mi < 4; ++mi)
            a[mi] = *(const f16x8*)&sA[cur][(wm + mi * 16 + lr) * 32 + lk];
#pragma unroll
        for (int ni = 0; ni < 4; ++ni)
            b[ni] = *(const f16x8*)&sB[cur][(wn + ni * 16 + lr) * 32 + lk];

#pragma unroll
        for (int mi = 0; mi < 4; ++mi)
#pragma unroll
            for (int ni = 0; ni < 4; ++ni)
                acc[mi][ni] = __builtin_amdgcn_mfma_f32_16x16x32_f16(
                    a[mi], b[ni], acc[mi][ni], 0, 0, 0);

        if (kt + 1 < NT) swrite(cur ^ 1);
    }

#pragma unroll
    for (int mi = 0; mi < 4; ++mi) {
#pragma unroll
        for (int ni = 0; ni < 4; ++ni) {
            const int row = m0 + wm + mi * 16 + (l >> 4) * 4;
            const int col = n0 + wn + ni * 16 + lr;
#pragma unroll
            for (int r2 = 0; r2 < 4; ++r2)
                C[(size_t)(row + r2) * NDIM + col] = acc[mi][ni][r2];
        }
    }
}

extern "C" void kernel_launch(void* const* d_in, const int* in_sizes, int n_in,
                              void* d_out, int out_size, void* d_ws, size_t ws_size,
                              hipStream_t stream) {
    const float* x     = (const float*)d_in[0];
    const float* scale = (const float*)d_in[1];
    const int*   qw    = (const int*)d_in[2];
    float*       out   = (float*)d_out;

    const size_t wtBytes = (size_t)NDIM * KDIM * 2;  // 32 MB
    const size_t xhBytes = (size_t)MDIM * KDIM * 2;  // 32 MB

    if (ws_size >= wtBytes + xhBytes) {
        unsigned short* wt = (unsigned short*)d_ws;
        unsigned short* xh = (unsigned short*)((char*)d_ws + wtBytes);
        convert_x<<<2048, 256, 0, stream>>>(x, xh, MDIM * KDIM / 8);
        dequant_transpose<<<dim3(KDIM / 64, NDIM / 64), 256, 0, stream>>>(qw, scale, wt);
        gemm_8w<<<dim3(256), 512, 0, stream>>>(xh, wt, out);
    } else if (ws_size >= wtBytes) {
        unsigned short* wt = (unsigned short*)d_ws;
        dequant_transpose<<<dim3(KDIM / 64, NDIM / 64), 256, 0, stream>>>(qw, scale, wt);
        gemm_bt<<<dim3(NDIM / 128, MDIM / 128), 256, 0, stream>>>(x, wt, out);
    } else {
        zero_fill<<<(out_size + 255) / 256, 256, 0, stream>>>(out, out_size);
    }
}